// Round 3
// baseline (322.531 us; speedup 1.0000x reference)
//
#include <hip/hip_runtime.h>
#include <hip/hip_bf16.h>
#include <stdint.h>

typedef __attribute__((ext_vector_type(4))) float f32x4;
typedef __attribute__((ext_vector_type(8))) short s16x8;
typedef __attribute__((ext_vector_type(4))) unsigned int u32x4;
typedef unsigned short u16;
typedef unsigned int u32;

#define B_ 4
#define C_ 256
#define O_ 256
#define H_ 96
#define W_ 96
#define HW_ (H_*W_)      /* 9216 */
#define M_ (B_*HW_)      /* 36864 */

static __device__ __forceinline__ float asf(u32 u){
    union { u32 u; float f; } x; x.u = u; return x.f;
}
static __device__ __forceinline__ u16 f2bf(float f){
    union { float f; u32 u; } x; x.f = f;
    u32 u = x.u;
    u32 r = (u + 0x7fffu + ((u >> 16) & 1u)) >> 16;
    return (u16)r;
}

// ---------------------------------------------------------------------------
// Kernel 1: transpose x [B,C,H,W] f32 -> xT [B,H,W,C] bf16
// ---------------------------------------------------------------------------
__global__ __launch_bounds__(256) void transpose_x(const float* __restrict__ x,
                                                   u16* __restrict__ xT)
{
    __shared__ float t[32][33];
    int tid = threadIdx.x;
    int tx = tid & 31, ty = tid >> 5;          // 32 x 8
    int bi = blockIdx.x;
    int w0 = (bi % 3) * 32;
    int c0 = ((bi / 3) % 8) * 32;
    int bh = bi / 24;                           // b*H + h  (0..383)
    int b = bh / H_, h = bh - b * H_;
    #pragma unroll
    for (int r = 0; r < 4; ++r){
        int c = c0 + ty + r * 8;
        t[ty + r * 8][tx] = x[(size_t)(b * C_ + c) * HW_ + h * W_ + w0 + tx];
    }
    __syncthreads();
    #pragma unroll
    for (int r = 0; r < 4; ++r){
        int w = w0 + ty + r * 8;
        xT[((size_t)(b * H_ + h) * W_ + w) * C_ + c0 + tx] = f2bf(t[tx][ty + r * 8]);
    }
}

// ---------------------------------------------------------------------------
// Kernel 2: pack weight [O,C,3,3] f32 -> W3 bf16, layout:
//   kidx = tap*256 + c ; flat u16 index = (kidx>>3)*2048 + o*8 + (kidx&7)
// ---------------------------------------------------------------------------
__global__ __launch_bounds__(256) void pack_w(const float* __restrict__ wt,
                                              u16* __restrict__ w3)
{
    int n = blockIdx.x * 256 + threadIdx.x;     // < 589824 = 256*256*9
    int o = n / 2304;
    int rem = n - o * 2304;
    int c = rem / 9;
    int tap = rem - c * 9;
    int kidx = tap * 256 + c;
    w3[(size_t)(kidx >> 3) * 2048 + o * 8 + (kidx & 7)] = f2bf(wt[n]);
}

// ---------------------------------------------------------------------------
// Kernel 3: main deformable-conv implicit GEMM.
// 576 blocks; block = one 8x8 pixel patch. XCD-contiguous tile assignment:
// tile = (bid%8)*72 + bid/8  -> each XCD owns half of one image (~2.4 MB L2).
// 4 blocks/CU (128 KB LDS) for cross-block gather/MFMA overlap.
// ---------------------------------------------------------------------------
__global__ __launch_bounds__(256, 4) void dcn_main(
    const float* __restrict__ off, const float* __restrict__ msk,
    const u16* __restrict__ xT, const u16* __restrict__ w3,
    float* __restrict__ convOut, float* __restrict__ stats)
{
    __shared__ u16 A[64 * 256];   // 32 KB, XOR-swizzled rows of 512B
    int tid = threadIdx.x;
    int lane = tid & 63;
    int wv = tid >> 6;            // 0..3 : n-block

    // ---- tile -> (b, patch) with XCD-contiguous assignment ----
    int bid = blockIdx.x;
    int tile = (bid & 7) * 72 + (bid >> 3);     // 576 = 8 * 72, bijective
    int b = tile / 144;
    int t = tile - b * 144;
    int ty_ = t / 12;
    int tx_ = t - ty_ * 12;
    int py0 = ty_ * 8;
    int px0 = tx_ * 8;

    f32x4 acc[4][4];
    #pragma unroll
    for (int i = 0; i < 4; ++i)
        #pragma unroll
        for (int q = 0; q < 4; ++q)
            acc[i][q] = (f32x4){0.f, 0.f, 0.f, 0.f};

    // gather assignment: 4 threads per pixel, 64 channels each
    int p = tid >> 2;             // pixel 0..63 within patch
    int h = py0 + (p >> 3);
    int w = px0 + (p & 7);
    int hw = h * W_ + w;
    int c0 = (tid & 3) * 64;

    for (int tap = 0; tap < 9; ++tap){
        __syncthreads();  // previous tap's LDS reads complete
        // ---- gather this tap's A-tile ----
        float dy = off[(size_t)(b * 18 + 2 * tap) * HW_ + hw];
        float dx = off[(size_t)(b * 18 + 2 * tap + 1) * HW_ + hw];
        float mk = msk[(size_t)(b * 9 + tap) * HW_ + hw];
        float py = (float)(h + tap / 3 - 1) + dy;
        float px = (float)(w + tap % 3 - 1) + dx;
        float fy = floorf(py), fx = floorf(px);
        float wy = py - fy, wx = px - fx;
        int y0 = (int)fy, x0 = (int)fx;
        int y1 = y0 + 1, x1 = x0 + 1;
        float w00 = (1.f - wy) * (1.f - wx) * mk;
        float w01 = (1.f - wy) * wx * mk;
        float w10 = wy * (1.f - wx) * mk;
        float w11 = wy * wx * mk;
        if (y0 < 0 || y0 >= H_) { w00 = 0.f; w01 = 0.f; }
        if (y1 < 0 || y1 >= H_) { w10 = 0.f; w11 = 0.f; }
        if (x0 < 0 || x0 >= W_) { w00 = 0.f; w10 = 0.f; }
        if (x1 < 0 || x1 >= W_) { w01 = 0.f; w11 = 0.f; }
        int cy0 = min(max(y0, 0), H_ - 1), cy1 = min(max(y1, 0), H_ - 1);
        int cx0 = min(max(x0, 0), W_ - 1), cx1 = min(max(x1, 0), W_ - 1);
        size_t rb = (size_t)b * HW_ * C_;
        const u16* r00 = xT + rb + ((size_t)cy0 * W_ + cx0) * C_;
        const u16* r01 = xT + rb + ((size_t)cy0 * W_ + cx1) * C_;
        const u16* r10 = xT + rb + ((size_t)cy1 * W_ + cx0) * C_;
        const u16* r11 = xT + rb + ((size_t)cy1 * W_ + cx1) * C_;
        #pragma unroll
        for (int i = 0; i < 8; ++i){
            int c = c0 + i * 8;
            u32x4 v00 = *(const u32x4*)(r00 + c);
            u32x4 v01 = *(const u32x4*)(r01 + c);
            u32x4 v10 = *(const u32x4*)(r10 + c);
            u32x4 v11 = *(const u32x4*)(r11 + c);
            u32x4 outv;
            #pragma unroll
            for (int j = 0; j < 4; ++j){
                // low bf16 of each pair: shift up; high bf16: reinterpret raw
                // u32 (low 16 bits perturb < 1 bf16 ulp — harmless here).
                float f0 = asf(v00[j] << 16) * w00 + asf(v01[j] << 16) * w01
                         + asf(v10[j] << 16) * w10 + asf(v11[j] << 16) * w11;
                float f1 = asf(v00[j]) * w00 + asf(v01[j]) * w01
                         + asf(v10[j]) * w10 + asf(v11[j]) * w11;
                float2 fp; fp.x = f0; fp.y = f1;
                __hip_bfloat162 hb = __float22bfloat162_rn(fp);
                union { __hip_bfloat162 h; u32 u; } cv; cv.h = hb;
                outv[j] = cv.u;
            }
            u32 boff = (u32)(p * 512 + c * 2);
            boff ^= (u32)((p & 7) << 4);
            *(u32x4*)((char*)A + boff) = outv;
        }
        __syncthreads();
        // ---- MFMA over this tap's K=256 chunk ----
        int g = lane >> 4;
        #pragma unroll
        for (int step = 0; step < 8; ++step){
            s16x8 a[4];
            int akb = (step * 32 + g * 8) * 2;
            #pragma unroll
            for (int i = 0; i < 4; ++i){
                int r = i * 16 + (lane & 15);
                u32 boff = (u32)(r * 512 + akb) ^ (u32)((r & 7) << 4);
                a[i] = *(const s16x8*)((const char*)A + boff);
            }
            const u16* wrow = w3 + (size_t)(tap * 32 + step * 4 + g) * 2048
                            + (wv * 64 + (lane & 15)) * 8;
            s16x8 bq[4];
            #pragma unroll
            for (int q = 0; q < 4; ++q)
                bq[q] = *(const s16x8*)(wrow + q * 128);
            #pragma unroll
            for (int i = 0; i < 4; ++i)
                #pragma unroll
                for (int q = 0; q < 4; ++q)
                    acc[i][q] = __builtin_amdgcn_mfma_f32_16x16x32_bf16(
                        a[i], bq[q], acc[i][q], 0, 0, 0);
        }
    }

    // ---- epilogue: store conv f32 at global [m][o], accumulate GN stats ----
    int rbase = (lane >> 4) * 4;
    int cbase = wv * 64 + (lane & 15);
    float s0 = 0.f, s20 = 0.f, s1 = 0.f, s21 = 0.f;
    size_t mbase = (size_t)b * HW_;
    #pragma unroll
    for (int i = 0; i < 4; ++i){
        #pragma unroll
        for (int q = 0; q < 4; ++q){
            int oc = cbase + q * 16;
            #pragma unroll
            for (int j = 0; j < 4; ++j){
                float v = acc[i][q][j];
                int pp = i * 16 + rbase + j;              // pixel in patch
                int mr_hw = (py0 + (pp >> 3)) * W_ + px0 + (pp & 7);
                convOut[(mbase + mr_hw) * 256 + oc] = v;
                if (q < 2) { s0 += v; s20 += v * v; }
                else       { s1 += v; s21 += v * v; }
            }
        }
    }
    #pragma unroll
    for (int d = 32; d; d >>= 1){
        s0  += __shfl_xor(s0, d, 64);
        s20 += __shfl_xor(s20, d, 64);
        s1  += __shfl_xor(s1, d, 64);
        s21 += __shfl_xor(s21, d, 64);
    }
    if (lane == 0){
        int g0 = 2 * wv, g1 = 2 * wv + 1;
        atomicAdd(&stats[(b * 8 + g0) * 2 + 0], s0);
        atomicAdd(&stats[(b * 8 + g0) * 2 + 1], s20);
        atomicAdd(&stats[(b * 8 + g1) * 2 + 0], s1);
        atomicAdd(&stats[(b * 8 + g1) * 2 + 1], s21);
    }
}

// ---------------------------------------------------------------------------
// Kernel 4: GroupNorm(8) + ReLU, transposing [m][o] -> [b,o,h,w]
// ---------------------------------------------------------------------------
__global__ __launch_bounds__(256) void gn_final(
    const float* __restrict__ convOut, const float* __restrict__ stats,
    const float* __restrict__ gamma, const float* __restrict__ beta,
    float* __restrict__ out)
{
    __shared__ float t[64][257];
    int tid = threadIdx.x;
    int m0 = blockIdx.x * 64;
    int b = m0 / HW_;
    const f32x4* src = (const f32x4*)(convOut + (size_t)m0 * 256);
    #pragma unroll
    for (int it = 0; it < 16; ++it){
        int idx = it * 256 + tid;
        int r = idx >> 6;
        int c4 = idx & 63;
        f32x4 v = src[(size_t)r * 64 + c4];
        t[r][c4 * 4 + 0] = v[0];
        t[r][c4 * 4 + 1] = v[1];
        t[r][c4 * 4 + 2] = v[2];
        t[r][c4 * 4 + 3] = v[3];
    }
    __syncthreads();
    int lanem = tid & 63;
    int hw = (m0 - b * HW_) + lanem;
    float* dst = out + (size_t)b * O_ * HW_ + hw;
    const float invN = 1.f / 294912.f;   // 32 ch * 9216 px
    #pragma unroll 8
    for (int it = 0; it < 64; ++it){
        int o = it * 4 + (tid >> 6);
        int gidx = (b * 8 + (o >> 5)) * 2;
        float sm = stats[gidx + 0];
        float sq = stats[gidx + 1];
        float mu = sm * invN;
        float var = sq * invN - mu * mu;
        float inv = rsqrtf(var + 1e-5f);
        float sc = gamma[o] * inv;
        float sh = beta[o] - mu * sc;
        float v = t[lanem][o];
        dst[(size_t)o * HW_] = fmaxf(v * sc + sh, 0.f);
    }
}

// ---------------------------------------------------------------------------
extern "C" void kernel_launch(void* const* d_in, const int* in_sizes, int n_in,
                              void* d_out, int out_size, void* d_ws, size_t ws_size,
                              hipStream_t stream)
{
    const float* x     = (const float*)d_in[0];
    const float* off   = (const float*)d_in[1];
    const float* msk   = (const float*)d_in[2];
    const float* wt    = (const float*)d_in[3];
    const float* gamma = (const float*)d_in[4];
    const float* beta  = (const float*)d_in[5];
    float* out = (float*)d_out;

    char* ws = (char*)d_ws;
    u16*   xT      = (u16*)ws;                       // 18,874,368 B
    u16*   w3      = (u16*)(ws + 18874368);          //  1,179,648 B
    float* convOut = (float*)(ws + 20054016);        // 37,748,736 B
    float* stats   = (float*)(ws + 57802752);        //        256 B

    hipMemsetAsync(stats, 0, 256, stream);
    hipLaunchKernelGGL(transpose_x, dim3(9216), dim3(256), 0, stream, x, xT);
    hipLaunchKernelGGL(pack_w,      dim3(2304), dim3(256), 0, stream, wt, w3);
    hipLaunchKernelGGL(dcn_main,    dim3(576),  dim3(256), 0, stream,
                       off, msk, xT, w3, convOut, stats);
    hipLaunchKernelGGL(gn_final,    dim3(576),  dim3(256), 0, stream,
                       convOut, stats, gamma, beta, out);
}

// Round 4
// 287.221 us; speedup vs baseline: 1.1229x; 1.1229x over previous
//
#include <hip/hip_runtime.h>
#include <hip/hip_bf16.h>
#include <stdint.h>

typedef __attribute__((ext_vector_type(4))) float f32x4;
typedef __attribute__((ext_vector_type(8))) short s16x8;
typedef __attribute__((ext_vector_type(4))) unsigned int u32x4;
typedef unsigned short u16;
typedef unsigned int u32;

#define B_ 4
#define C_ 256
#define O_ 256
#define H_ 96
#define W_ 96
#define HW_ (H_*W_)      /* 9216 */
#define M_ (B_*HW_)      /* 36864 */

static __device__ __forceinline__ float asf(u32 u){
    union { u32 u; float f; } x; x.u = u; return x.f;
}
static __device__ __forceinline__ u16 f2bf(float f){
    union { float f; u32 u; } x; x.f = f;
    u32 u = x.u;
    u32 r = (u + 0x7fffu + ((u >> 16) & 1u)) >> 16;
    return (u16)r;
}
// bilinear-combine a bf16 pair (packed in u32) from 4 source pairs, repack
static __device__ __forceinline__ u32 blerp_pack(u32 q00, u32 q01, u32 q10, u32 q11,
                                                 float w00, float w01, float w10, float w11)
{
    // low bf16: shift up; high bf16: reinterpret raw u32 (low 16 bits < 1 ulp)
    float f0 = asf(q00 << 16) * w00 + asf(q01 << 16) * w01
             + asf(q10 << 16) * w10 + asf(q11 << 16) * w11;
    float f1 = asf(q00) * w00 + asf(q01) * w01 + asf(q10) * w10 + asf(q11) * w11;
    float2 fp; fp.x = f0; fp.y = f1;
    __hip_bfloat162 hb = __float22bfloat162_rn(fp);
    union { __hip_bfloat162 h; u32 u; } cv; cv.h = hb;
    return cv.u;
}

struct TapCtx {
    float w00, w01, w10, w11;
    const u16 *r00, *r01, *r10, *r11;
};

static __device__ __forceinline__ TapCtx tap_setup(
    int tap, int b, int h, int w, int hw,
    const float* __restrict__ off, const float* __restrict__ msk,
    const u16* __restrict__ xT)
{
    TapCtx t;
    float dy = off[(size_t)(b * 18 + 2 * tap) * HW_ + hw];
    float dx = off[(size_t)(b * 18 + 2 * tap + 1) * HW_ + hw];
    float mk = msk[(size_t)(b * 9 + tap) * HW_ + hw];
    float py = (float)(h + tap / 3 - 1) + dy;
    float px = (float)(w + tap % 3 - 1) + dx;
    float fy = floorf(py), fx = floorf(px);
    float wy = py - fy, wx = px - fx;
    int y0 = (int)fy, x0 = (int)fx;
    int y1 = y0 + 1, x1 = x0 + 1;
    float w00 = (1.f - wy) * (1.f - wx) * mk;
    float w01 = (1.f - wy) * wx * mk;
    float w10 = wy * (1.f - wx) * mk;
    float w11 = wy * wx * mk;
    if (y0 < 0 || y0 >= H_) { w00 = 0.f; w01 = 0.f; }
    if (y1 < 0 || y1 >= H_) { w10 = 0.f; w11 = 0.f; }
    if (x0 < 0 || x0 >= W_) { w00 = 0.f; w10 = 0.f; }
    if (x1 < 0 || x1 >= W_) { w01 = 0.f; w11 = 0.f; }
    int cy0 = min(max(y0, 0), H_ - 1), cy1 = min(max(y1, 0), H_ - 1);
    int cx0 = min(max(x0, 0), W_ - 1), cx1 = min(max(x1, 0), W_ - 1);
    size_t rb = (size_t)b * HW_ * C_;
    t.r00 = xT + rb + ((size_t)cy0 * W_ + cx0) * C_;
    t.r01 = xT + rb + ((size_t)cy0 * W_ + cx1) * C_;
    t.r10 = xT + rb + ((size_t)cy1 * W_ + cx0) * C_;
    t.r11 = xT + rb + ((size_t)cy1 * W_ + cx1) * C_;
    t.w00 = w00; t.w01 = w01; t.w10 = w10; t.w11 = w11;
    return t;
}

// ---------------------------------------------------------------------------
// Kernel 1: transpose x [B,C,H,W] f32 -> xT [B,H,W,C] bf16
// ---------------------------------------------------------------------------
__global__ __launch_bounds__(256) void transpose_x(const float* __restrict__ x,
                                                   u16* __restrict__ xT)
{
    __shared__ float t[32][33];
    int tid = threadIdx.x;
    int tx = tid & 31, ty = tid >> 5;          // 32 x 8
    int bi = blockIdx.x;
    int w0 = (bi % 3) * 32;
    int c0 = ((bi / 3) % 8) * 32;
    int bh = bi / 24;                           // b*H + h  (0..383)
    int b = bh / H_, h = bh - b * H_;
    #pragma unroll
    for (int r = 0; r < 4; ++r){
        int c = c0 + ty + r * 8;
        t[ty + r * 8][tx] = x[(size_t)(b * C_ + c) * HW_ + h * W_ + w0 + tx];
    }
    __syncthreads();
    #pragma unroll
    for (int r = 0; r < 4; ++r){
        int w = w0 + ty + r * 8;
        xT[((size_t)(b * H_ + h) * W_ + w) * C_ + c0 + tx] = f2bf(t[tx][ty + r * 8]);
    }
}

// ---------------------------------------------------------------------------
// Kernel 2: pack weight [O,C,3,3] f32 -> W3 bf16:
//   kidx = tap*256 + c ; flat u16 index = (kidx>>3)*2048 + o*8 + (kidx&7)
// ---------------------------------------------------------------------------
__global__ __launch_bounds__(256) void pack_w(const float* __restrict__ wt,
                                              u16* __restrict__ w3)
{
    int n = blockIdx.x * 256 + threadIdx.x;     // < 589824 = 256*256*9
    int o = n / 2304;
    int rem = n - o * 2304;
    int c = rem / 9;
    int tap = rem - c * 9;
    int kidx = tap * 256 + c;
    w3[(size_t)(kidx >> 3) * 2048 + o * 8 + (kidx & 7)] = f2bf(wt[n]);
}

// ---------------------------------------------------------------------------
// Kernel 3: main deformable-conv implicit GEMM.
// 1152 blocks; block = one 8(w)x4(h) pixel patch (BM=32). XCD-contiguous:
// tile = (bid&7)*144 + bid>>3 -> each XCD owns half an image (~2.4 MB L2).
// Double-buffered LDS (2x16KB) + register-staged prefetch of next tap's
// gather, interleaved around two 4-step MFMA clusters (T14 issue-early/
// write-late). One barrier per tap.
// ---------------------------------------------------------------------------
__global__ __launch_bounds__(256, 2) void dcn_main(
    const float* __restrict__ off, const float* __restrict__ msk,
    const u16* __restrict__ xT, const u16* __restrict__ w3,
    float* __restrict__ convOut, float* __restrict__ stats)
{
    __shared__ u16 A[2][32 * 256];   // 2 x 16 KB, XOR-swizzled rows of 512B
    int tid = threadIdx.x;
    int lane = tid & 63;
    int wv = tid >> 6;               // 0..3 : n-block

    int bid = blockIdx.x;
    int tile = (bid & 7) * 144 + (bid >> 3);    // 1152 = 8*144, bijective
    int b = tile / 288;
    int t = tile - b * 288;
    int ty_ = t / 12, tx_ = t - ty_ * 12;
    int py0 = ty_ * 4, px0 = tx_ * 8;

    f32x4 acc[2][4];
    #pragma unroll
    for (int i = 0; i < 2; ++i)
        #pragma unroll
        for (int q = 0; q < 4; ++q)
            acc[i][q] = (f32x4){0.f, 0.f, 0.f, 0.f};

    // gather assignment: 8 threads per pixel, 32 channels each
    int p = tid >> 3;                // pixel 0..31 within patch
    int h = py0 + (p >> 3);
    int w = px0 + (p & 7);
    int hw = h * W_ + w;
    int c0 = (tid & 7) * 32;

    // ---- prologue: gather tap 0 into A[0] ----
    {
        TapCtx tp = tap_setup(0, b, h, w, hw, off, msk, xT);
        #pragma unroll
        for (int i = 0; i < 4; ++i){
            int c = c0 + i * 8;
            u32x4 q00 = *(const u32x4*)(tp.r00 + c);
            u32x4 q01 = *(const u32x4*)(tp.r01 + c);
            u32x4 q10 = *(const u32x4*)(tp.r10 + c);
            u32x4 q11 = *(const u32x4*)(tp.r11 + c);
            u32x4 outv;
            #pragma unroll
            for (int j = 0; j < 4; ++j)
                outv[j] = blerp_pack(q00[j], q01[j], q10[j], q11[j],
                                     tp.w00, tp.w01, tp.w10, tp.w11);
            u32 boff = ((u32)(p * 512 + c * 2)) ^ ((u32)(p & 7) << 4);
            *(u32x4*)((char*)&A[0][0] + boff) = outv;
        }
    }
    __syncthreads();

    int g = lane >> 4;
    int l15 = lane & 15;

    int cur = 0;
    for (int tap = 0; tap < 9; ++tap){
        bool pre = (tap < 8);
        TapCtx tn;
        u32x4 s00[2], s01[2], s10[2], s11[2];
        if (pre){
            tn = tap_setup(tap + 1, b, h, w, hw, off, msk, xT);
            #pragma unroll
            for (int i = 0; i < 2; ++i){
                int c = c0 + i * 8;
                s00[i] = *(const u32x4*)(tn.r00 + c);
                s01[i] = *(const u32x4*)(tn.r01 + c);
                s10[i] = *(const u32x4*)(tn.r10 + c);
                s11[i] = *(const u32x4*)(tn.r11 + c);
            }
        }
        const char* Ac = (const char*)&A[cur][0];
        char* An = (char*)&A[cur ^ 1][0];

        // ---- MFMA steps 0..3 ----
        __builtin_amdgcn_s_setprio(1);
        #pragma unroll
        for (int step = 0; step < 4; ++step){
            int akb = (step * 32 + g * 8) * 2;
            u32 bo0 = (u32)(l15 * 512 + akb) ^ ((u32)(l15 & 7) << 4);
            u32 bo1 = (u32)((16 + l15) * 512 + akb) ^ ((u32)(l15 & 7) << 4);
            s16x8 a0 = *(const s16x8*)(Ac + bo0);
            s16x8 a1 = *(const s16x8*)(Ac + bo1);
            const u16* wrow = w3 + (size_t)(tap * 32 + step * 4 + g) * 2048
                            + (size_t)(wv * 64 + l15) * 8;
            s16x8 bq[4];
            #pragma unroll
            for (int q = 0; q < 4; ++q)
                bq[q] = *(const s16x8*)(wrow + q * 128);
            #pragma unroll
            for (int q = 0; q < 4; ++q){
                acc[0][q] = __builtin_amdgcn_mfma_f32_16x16x32_bf16(a0, bq[q], acc[0][q], 0, 0, 0);
                acc[1][q] = __builtin_amdgcn_mfma_f32_16x16x32_bf16(a1, bq[q], acc[1][q], 0, 0, 0);
            }
        }
        __builtin_amdgcn_s_setprio(0);

        if (pre){
            // commit half 0, then prefetch half 1
            #pragma unroll
            for (int i = 0; i < 2; ++i){
                int c = c0 + i * 8;
                u32x4 outv;
                #pragma unroll
                for (int j = 0; j < 4; ++j)
                    outv[j] = blerp_pack(s00[i][j], s01[i][j], s10[i][j], s11[i][j],
                                         tn.w00, tn.w01, tn.w10, tn.w11);
                u32 boff = ((u32)(p * 512 + c * 2)) ^ ((u32)(p & 7) << 4);
                *(u32x4*)(An + boff) = outv;
            }
            #pragma unroll
            for (int i = 0; i < 2; ++i){
                int c = c0 + (i + 2) * 8;
                s00[i] = *(const u32x4*)(tn.r00 + c);
                s01[i] = *(const u32x4*)(tn.r01 + c);
                s10[i] = *(const u32x4*)(tn.r10 + c);
                s11[i] = *(const u32x4*)(tn.r11 + c);
            }
        }

        // ---- MFMA steps 4..7 ----
        __builtin_amdgcn_s_setprio(1);
        #pragma unroll
        for (int step = 4; step < 8; ++step){
            int akb = (step * 32 + g * 8) * 2;
            u32 bo0 = (u32)(l15 * 512 + akb) ^ ((u32)(l15 & 7) << 4);
            u32 bo1 = (u32)((16 + l15) * 512 + akb) ^ ((u32)(l15 & 7) << 4);
            s16x8 a0 = *(const s16x8*)(Ac + bo0);
            s16x8 a1 = *(const s16x8*)(Ac + bo1);
            const u16* wrow = w3 + (size_t)(tap * 32 + step * 4 + g) * 2048
                            + (size_t)(wv * 64 + l15) * 8;
            s16x8 bq[4];
            #pragma unroll
            for (int q = 0; q < 4; ++q)
                bq[q] = *(const s16x8*)(wrow + q * 128);
            #pragma unroll
            for (int q = 0; q < 4; ++q){
                acc[0][q] = __builtin_amdgcn_mfma_f32_16x16x32_bf16(a0, bq[q], acc[0][q], 0, 0, 0);
                acc[1][q] = __builtin_amdgcn_mfma_f32_16x16x32_bf16(a1, bq[q], acc[1][q], 0, 0, 0);
            }
        }
        __builtin_amdgcn_s_setprio(0);

        if (pre){
            // commit half 1
            #pragma unroll
            for (int i = 0; i < 2; ++i){
                int c = c0 + (i + 2) * 8;
                u32x4 outv;
                #pragma unroll
                for (int j = 0; j < 4; ++j)
                    outv[j] = blerp_pack(s00[i][j], s01[i][j], s10[i][j], s11[i][j],
                                         tn.w00, tn.w01, tn.w10, tn.w11);
                u32 boff = ((u32)(p * 512 + c * 2)) ^ ((u32)(p & 7) << 4);
                *(u32x4*)(An + boff) = outv;
            }
        }
        __syncthreads();
        cur ^= 1;
    }

    // ---- epilogue: store conv f32 at global [m][o], accumulate GN stats ----
    int rbase = (lane >> 4) * 4;
    int cbase = wv * 64 + l15;
    float s0 = 0.f, s20 = 0.f, s1 = 0.f, s21 = 0.f;
    size_t mbase = (size_t)b * HW_;
    #pragma unroll
    for (int i = 0; i < 2; ++i){
        #pragma unroll
        for (int q = 0; q < 4; ++q){
            int oc = cbase + q * 16;
            #pragma unroll
            for (int j = 0; j < 4; ++j){
                float v = acc[i][q][j];
                int pp = i * 16 + rbase + j;              // pixel in patch
                int mr_hw = (py0 + (pp >> 3)) * W_ + px0 + (pp & 7);
                convOut[(mbase + mr_hw) * 256 + oc] = v;
                if (q < 2) { s0 += v; s20 += v * v; }
                else       { s1 += v; s21 += v * v; }
            }
        }
    }
    #pragma unroll
    for (int d = 32; d; d >>= 1){
        s0  += __shfl_xor(s0, d, 64);
        s20 += __shfl_xor(s20, d, 64);
        s1  += __shfl_xor(s1, d, 64);
        s21 += __shfl_xor(s21, d, 64);
    }
    if (lane == 0){
        int g0 = 2 * wv, g1 = 2 * wv + 1;
        atomicAdd(&stats[(b * 8 + g0) * 2 + 0], s0);
        atomicAdd(&stats[(b * 8 + g0) * 2 + 1], s20);
        atomicAdd(&stats[(b * 8 + g1) * 2 + 0], s1);
        atomicAdd(&stats[(b * 8 + g1) * 2 + 1], s21);
    }
}

// ---------------------------------------------------------------------------
// Kernel 4: GroupNorm(8) + ReLU, transposing [m][o] -> [b,o,h,w]
// ---------------------------------------------------------------------------
__global__ __launch_bounds__(256) void gn_final(
    const float* __restrict__ convOut, const float* __restrict__ stats,
    const float* __restrict__ gamma, const float* __restrict__ beta,
    float* __restrict__ out)
{
    __shared__ float t[64][257];
    int tid = threadIdx.x;
    int m0 = blockIdx.x * 64;
    int b = m0 / HW_;
    const f32x4* src = (const f32x4*)(convOut + (size_t)m0 * 256);
    #pragma unroll
    for (int it = 0; it < 16; ++it){
        int idx = it * 256 + tid;
        int r = idx >> 6;
        int c4 = idx & 63;
        f32x4 v = src[(size_t)r * 64 + c4];
        t[r][c4 * 4 + 0] = v[0];
        t[r][c4 * 4 + 1] = v[1];
        t[r][c4 * 4 + 2] = v[2];
        t[r][c4 * 4 + 3] = v[3];
    }
    __syncthreads();
    int lanem = tid & 63;
    int hw = (m0 - b * HW_) + lanem;
    float* dst = out + (size_t)b * O_ * HW_ + hw;
    const float invN = 1.f / 294912.f;   // 32 ch * 9216 px
    #pragma unroll 8
    for (int it = 0; it < 64; ++it){
        int o = it * 4 + (tid >> 6);
        int gidx = (b * 8 + (o >> 5)) * 2;
        float sm = stats[gidx + 0];
        float sq = stats[gidx + 1];
        float mu = sm * invN;
        float var = sq * invN - mu * mu;
        float inv = rsqrtf(var + 1e-5f);
        float sc = gamma[o] * inv;
        float sh = beta[o] - mu * sc;
        float v = t[lanem][o];
        dst[(size_t)o * HW_] = fmaxf(v * sc + sh, 0.f);
    }
}

// ---------------------------------------------------------------------------
extern "C" void kernel_launch(void* const* d_in, const int* in_sizes, int n_in,
                              void* d_out, int out_size, void* d_ws, size_t ws_size,
                              hipStream_t stream)
{
    const float* x     = (const float*)d_in[0];
    const float* off   = (const float*)d_in[1];
    const float* msk   = (const float*)d_in[2];
    const float* wt    = (const float*)d_in[3];
    const float* gamma = (const float*)d_in[4];
    const float* beta  = (const float*)d_in[5];
    float* out = (float*)d_out;

    char* ws = (char*)d_ws;
    u16*   xT      = (u16*)ws;                       // 18,874,368 B
    u16*   w3      = (u16*)(ws + 18874368);          //  1,179,648 B
    float* convOut = (float*)(ws + 20054016);        // 37,748,736 B
    float* stats   = (float*)(ws + 57802752);        //        256 B

    hipMemsetAsync(stats, 0, 256, stream);
    hipLaunchKernelGGL(transpose_x, dim3(9216), dim3(256), 0, stream, x, xT);
    hipLaunchKernelGGL(pack_w,      dim3(2304), dim3(256), 0, stream, wt, w3);
    hipLaunchKernelGGL(dcn_main,    dim3(1152), dim3(256), 0, stream,
                       off, msk, xT, w3, convOut, stats);
    hipLaunchKernelGGL(gn_final,    dim3(576),  dim3(256), 0, stream,
                       convOut, stats, gamma, beta, out);
}

// Round 5
// 216.237 us; speedup vs baseline: 1.4916x; 1.3283x over previous
//
#include <hip/hip_runtime.h>
#include <hip/hip_bf16.h>
#include <stdint.h>

typedef __attribute__((ext_vector_type(4))) float f32x4;
typedef __attribute__((ext_vector_type(8))) short s16x8;
typedef __attribute__((ext_vector_type(4))) unsigned int u32x4;
typedef unsigned short u16;
typedef unsigned int u32;

#define B_ 4
#define C_ 256
#define O_ 256
#define H_ 96
#define W_ 96
#define HW_ (H_*W_)      /* 9216 */
#define M_ (B_*HW_)      /* 36864 */

static __device__ __forceinline__ float asf(u32 u){
    union { u32 u; float f; } x; x.u = u; return x.f;
}
static __device__ __forceinline__ u16 f2bf(float f){
    union { float f; u32 u; } x; x.f = f;
    u32 u = x.u;
    u32 r = (u + 0x7fffu + ((u >> 16) & 1u)) >> 16;
    return (u16)r;
}
// bilinear-combine a bf16 pair (packed in u32) from 4 source pairs, repack
static __device__ __forceinline__ u32 blerp_pack(u32 q00, u32 q01, u32 q10, u32 q11,
                                                 float w00, float w01, float w10, float w11)
{
    float f0 = asf(q00 << 16) * w00 + asf(q01 << 16) * w01
             + asf(q10 << 16) * w10 + asf(q11 << 16) * w11;
    float f1 = asf(q00) * w00 + asf(q01) * w01 + asf(q10) * w10 + asf(q11) * w11;
    float2 fp; fp.x = f0; fp.y = f1;
    __hip_bfloat162 hb = __float22bfloat162_rn(fp);
    union { __hip_bfloat162 h; u32 u; } cv; cv.h = hb;
    return cv.u;
}

// ---------------------------------------------------------------------------
// Kernel 1: transpose x [B,C,H,W] f32 -> xT [B,H,W,C] bf16
// ---------------------------------------------------------------------------
__global__ __launch_bounds__(256) void transpose_x(const float* __restrict__ x,
                                                   u16* __restrict__ xT)
{
    __shared__ float t[32][33];
    int tid = threadIdx.x;
    int tx = tid & 31, ty = tid >> 5;          // 32 x 8
    int bi = blockIdx.x;
    int w0 = (bi % 3) * 32;
    int c0 = ((bi / 3) % 8) * 32;
    int bh = bi / 24;                           // b*H + h  (0..383)
    int b = bh / H_, h = bh - b * H_;
    #pragma unroll
    for (int r = 0; r < 4; ++r){
        int c = c0 + ty + r * 8;
        t[ty + r * 8][tx] = x[(size_t)(b * C_ + c) * HW_ + h * W_ + w0 + tx];
    }
    __syncthreads();
    #pragma unroll
    for (int r = 0; r < 4; ++r){
        int w = w0 + ty + r * 8;
        xT[((size_t)(b * H_ + h) * W_ + w) * C_ + c0 + tx] = f2bf(t[tx][ty + r * 8]);
    }
}

// ---------------------------------------------------------------------------
// Kernel 2: pack weight [O,C,3,3] f32 -> W3 bf16:
//   kidx = tap*256 + c ; flat u16 index = (kidx>>3)*2048 + o*8 + (kidx&7)
// ---------------------------------------------------------------------------
__global__ __launch_bounds__(256) void pack_w(const float* __restrict__ wt,
                                              u16* __restrict__ w3)
{
    int n = blockIdx.x * 256 + threadIdx.x;     // < 589824 = 256*256*9
    int o = n / 2304;
    int rem = n - o * 2304;
    int c = rem / 9;
    int tap = rem - c * 9;
    int kidx = tap * 256 + c;
    w3[(size_t)(kidx >> 3) * 2048 + o * 8 + (kidx & 7)] = f2bf(wt[n]);
}

// ---------------------------------------------------------------------------
// Kernel 3: main deformable-conv implicit GEMM with LDS HALO staging.
// 576 blocks; block = 8x8 patch; XCD-contiguous tile = (bid&7)*72 + bid>>3.
// Per channel-half (128 ch): stage 16x16-row halo (64 KB) in LDS once
// (coalesced from L2), then per tap blend bilinear samples FROM LDS into a
// 16 KB A-tile, MFMA 4 K-steps. Out-of-halo samples (~0.02%) take a
// predicated global slow path with exact reference clamping.
// LDS 80 KB -> 2 blocks/CU. Gather L2 traffic 680 MB -> ~75 MB streaming.
// ---------------------------------------------------------------------------
__global__ __launch_bounds__(256, 2) void dcn_main(
    const float* __restrict__ off, const float* __restrict__ msk,
    const u16* __restrict__ xT, const u16* __restrict__ w3,
    float* __restrict__ convOut, float* __restrict__ stats)
{
    __shared__ u16 Hl[256 * 128];   // halo: 256 rows x 256B, 16B-chunk swizzled
    __shared__ u16 At[64 * 128];    // A-tile: 64 px x 256B, swizzled

    int tid = threadIdx.x;
    int lane = tid & 63;
    int wv = tid >> 6;               // 0..3 : output-channel block
    int l15 = lane & 15;
    int g = lane >> 4;

    int bid = blockIdx.x;
    int tile = (bid & 7) * 72 + (bid >> 3);     // 576 = 8*72, bijective
    int b = tile / 144;
    int t = tile - b * 144;
    int ty_ = t / 12, tx_ = t - ty_ * 12;
    int py0 = ty_ * 8, px0 = tx_ * 8;

    f32x4 acc[4][4];
    #pragma unroll
    for (int i = 0; i < 4; ++i)
        #pragma unroll
        for (int q = 0; q < 4; ++q)
            acc[i][q] = (f32x4){0.f, 0.f, 0.f, 0.f};

    // blend assignment: 4 threads per pixel, thread k handles chunks k,k+4,k+8,k+12
    int p = tid >> 2;                // pixel 0..63 within patch
    int k = tid & 3;
    int h = py0 + (p >> 3);
    int w = px0 + (p & 7);
    int hw = h * W_ + w;
    size_t rbimg = (size_t)b * HW_ * C_;
    int hy0 = py0 - 4, hx0 = px0 - 4;

    for (int cH = 0; cH < 2; ++cH){
        // ---- stage halo (coalesced; clamped rows at image edges) ----
        #pragma unroll
        for (int it = 0; it < 16; ++it){
            int u = it * 256 + tid;          // 0..4095 : (row, 16B-chunk)
            int row = u >> 4, ck = u & 15;
            int gy = min(max(hy0 + (row >> 4), 0), H_ - 1);
            int gx = min(max(hx0 + (row & 15), 0), W_ - 1);
            const u16* src = xT + rbimg + ((size_t)gy * W_ + gx) * C_ + cH * 128 + ck * 8;
            u32x4 v = *(const u32x4*)src;
            *(u32x4*)((char*)Hl + row * 256 + ((ck ^ (row & 15)) << 4)) = v;
        }
        __syncthreads();

        for (int tap = 0; tap < 9; ++tap){
            // ---- tap setup for this thread's pixel ----
            float dy = off[(size_t)(b * 18 + 2 * tap) * HW_ + hw];
            float dx = off[(size_t)(b * 18 + 2 * tap + 1) * HW_ + hw];
            float mk = msk[(size_t)(b * 9 + tap) * HW_ + hw];
            float py = (float)(h + tap / 3 - 1) + dy;
            float px = (float)(w + tap % 3 - 1) + dx;
            float fy = floorf(py), fx = floorf(px);
            float wy = py - fy, wx = px - fx;
            int y0 = (int)fy, x0 = (int)fx;
            int y1 = y0 + 1, x1 = x0 + 1;
            float w00 = (1.f - wy) * (1.f - wx) * mk;
            float w01 = (1.f - wy) * wx * mk;
            float w10 = wy * (1.f - wx) * mk;
            float w11 = wy * wx * mk;
            if (y0 < 0 || y0 >= H_) { w00 = 0.f; w01 = 0.f; }
            if (y1 < 0 || y1 >= H_) { w10 = 0.f; w11 = 0.f; }
            if (x0 < 0 || x0 >= W_) { w00 = 0.f; w10 = 0.f; }
            if (x1 < 0 || x1 >= W_) { w01 = 0.f; w11 = 0.f; }

            bool fast = (y0 >= hy0) && (y0 <= py0 + 10)
                     && (x0 >= hx0) && (x0 <= px0 + 10);
            int r00 = 0;
            const u16 *b00 = xT, *b01 = xT, *b10 = xT, *b11 = xT;
            if (fast){
                r00 = (y0 - hy0) * 16 + (x0 - hx0);
            } else {
                int cy0 = min(max(y0, 0), H_ - 1), cy1 = min(max(y1, 0), H_ - 1);
                int cx0 = min(max(x0, 0), W_ - 1), cx1 = min(max(x1, 0), W_ - 1);
                b00 = xT + rbimg + ((size_t)cy0 * W_ + cx0) * C_ + cH * 128;
                b01 = xT + rbimg + ((size_t)cy0 * W_ + cx1) * C_ + cH * 128;
                b10 = xT + rbimg + ((size_t)cy1 * W_ + cx0) * C_ + cH * 128;
                b11 = xT + rbimg + ((size_t)cy1 * W_ + cx1) * C_ + cH * 128;
            }

            #pragma unroll
            for (int i = 0; i < 4; ++i){
                int ck = k + 4 * i;
                u32x4 q00, q01, q10, q11;
                if (fast){
                    const char* Hb = (const char*)Hl;
                    int r01 = r00 + 1, r10 = r00 + 16, r11 = r00 + 17;
                    q00 = *(const u32x4*)(Hb + r00 * 256 + ((ck ^ (r00 & 15)) << 4));
                    q01 = *(const u32x4*)(Hb + r01 * 256 + ((ck ^ (r01 & 15)) << 4));
                    q10 = *(const u32x4*)(Hb + r10 * 256 + ((ck ^ (r10 & 15)) << 4));
                    q11 = *(const u32x4*)(Hb + r11 * 256 + ((ck ^ (r11 & 15)) << 4));
                } else {
                    q00 = *(const u32x4*)(b00 + ck * 8);
                    q01 = *(const u32x4*)(b01 + ck * 8);
                    q10 = *(const u32x4*)(b10 + ck * 8);
                    q11 = *(const u32x4*)(b11 + ck * 8);
                }
                u32x4 outv;
                #pragma unroll
                for (int j = 0; j < 4; ++j)
                    outv[j] = blerp_pack(q00[j], q01[j], q10[j], q11[j],
                                         w00, w01, w10, w11);
                *(u32x4*)((char*)At + p * 256 + ((ck ^ (p & 15)) << 4)) = outv;
            }
            __syncthreads();   // A-tile ready

            // ---- MFMA: 4 K-steps (128 channels) ----
            __builtin_amdgcn_s_setprio(1);
            #pragma unroll
            for (int s = 0; s < 4; ++s){
                s16x8 a[4];
                int ck = s * 4 + g;
                #pragma unroll
                for (int i = 0; i < 4; ++i){
                    int r = i * 16 + l15;
                    a[i] = *(const s16x8*)((const char*)At + r * 256 + ((ck ^ (r & 15)) << 4));
                }
                const u16* wrow = w3 + (size_t)(tap * 32 + cH * 16 + s * 4 + g) * 2048
                                + (size_t)(wv * 64 + l15) * 8;
                s16x8 bq[4];
                #pragma unroll
                for (int q = 0; q < 4; ++q)
                    bq[q] = *(const s16x8*)(wrow + q * 128);
                #pragma unroll
                for (int i = 0; i < 4; ++i)
                    #pragma unroll
                    for (int q = 0; q < 4; ++q)
                        acc[i][q] = __builtin_amdgcn_mfma_f32_16x16x32_bf16(
                            a[i], bq[q], acc[i][q], 0, 0, 0);
            }
            __builtin_amdgcn_s_setprio(0);
            __syncthreads();   // before next tap overwrites At (or next halo)
        }
    }

    // ---- epilogue: store conv f32 at global [m][o], accumulate GN stats ----
    int rbase = g * 4;
    int cbase = wv * 64 + l15;
    float s0 = 0.f, s20 = 0.f, s1 = 0.f, s21 = 0.f;
    size_t mbase = (size_t)b * HW_;
    #pragma unroll
    for (int i = 0; i < 4; ++i){
        #pragma unroll
        for (int q = 0; q < 4; ++q){
            int oc = cbase + q * 16;
            #pragma unroll
            for (int j = 0; j < 4; ++j){
                float v = acc[i][q][j];
                int pp = i * 16 + rbase + j;              // pixel in patch
                int mr_hw = (py0 + (pp >> 3)) * W_ + px0 + (pp & 7);
                convOut[(mbase + mr_hw) * 256 + oc] = v;
                if (q < 2) { s0 += v; s20 += v * v; }
                else       { s1 += v; s21 += v * v; }
            }
        }
    }
    #pragma unroll
    for (int d = 32; d; d >>= 1){
        s0  += __shfl_xor(s0, d, 64);
        s20 += __shfl_xor(s20, d, 64);
        s1  += __shfl_xor(s1, d, 64);
        s21 += __shfl_xor(s21, d, 64);
    }
    if (lane == 0){
        int g0 = 2 * wv, g1 = 2 * wv + 1;
        atomicAdd(&stats[(b * 8 + g0) * 2 + 0], s0);
        atomicAdd(&stats[(b * 8 + g0) * 2 + 1], s20);
        atomicAdd(&stats[(b * 8 + g1) * 2 + 0], s1);
        atomicAdd(&stats[(b * 8 + g1) * 2 + 1], s21);
    }
}

// ---------------------------------------------------------------------------
// Kernel 4: GroupNorm(8) + ReLU, transposing [m][o] -> [b,o,h,w]
// ---------------------------------------------------------------------------
__global__ __launch_bounds__(256) void gn_final(
    const float* __restrict__ convOut, const float* __restrict__ stats,
    const float* __restrict__ gamma, const float* __restrict__ beta,
    float* __restrict__ out)
{
    __shared__ float t[64][257];
    int tid = threadIdx.x;
    int m0 = blockIdx.x * 64;
    int b = m0 / HW_;
    const f32x4* src = (const f32x4*)(convOut + (size_t)m0 * 256);
    #pragma unroll
    for (int it = 0; it < 16; ++it){
        int idx = it * 256 + tid;
        int r = idx >> 6;
        int c4 = idx & 63;
        f32x4 v = src[(size_t)r * 64 + c4];
        t[r][c4 * 4 + 0] = v[0];
        t[r][c4 * 4 + 1] = v[1];
        t[r][c4 * 4 + 2] = v[2];
        t[r][c4 * 4 + 3] = v[3];
    }
    __syncthreads();
    int lanem = tid & 63;
    int hw = (m0 - b * HW_) + lanem;
    float* dst = out + (size_t)b * O_ * HW_ + hw;
    const float invN = 1.f / 294912.f;   // 32 ch * 9216 px
    #pragma unroll 8
    for (int it = 0; it < 64; ++it){
        int o = it * 4 + (tid >> 6);
        int gidx = (b * 8 + (o >> 5)) * 2;
        float sm = stats[gidx + 0];
        float sq = stats[gidx + 1];
        float mu = sm * invN;
        float var = sq * invN - mu * mu;
        float inv = rsqrtf(var + 1e-5f);
        float sc = gamma[o] * inv;
        float sh = beta[o] - mu * sc;
        float v = t[lanem][o];
        dst[(size_t)o * HW_] = fmaxf(v * sc + sh, 0.f);
    }
}

// ---------------------------------------------------------------------------
extern "C" void kernel_launch(void* const* d_in, const int* in_sizes, int n_in,
                              void* d_out, int out_size, void* d_ws, size_t ws_size,
                              hipStream_t stream)
{
    const float* x     = (const float*)d_in[0];
    const float* off   = (const float*)d_in[1];
    const float* msk   = (const float*)d_in[2];
    const float* wt    = (const float*)d_in[3];
    const float* gamma = (const float*)d_in[4];
    const float* beta  = (const float*)d_in[5];
    float* out = (float*)d_out;

    char* ws = (char*)d_ws;
    u16*   xT      = (u16*)ws;                       // 18,874,368 B
    u16*   w3      = (u16*)(ws + 18874368);          //  1,179,648 B
    float* convOut = (float*)(ws + 20054016);        // 37,748,736 B
    float* stats   = (float*)(ws + 57802752);        //        256 B

    hipMemsetAsync(stats, 0, 256, stream);
    hipLaunchKernelGGL(transpose_x, dim3(9216), dim3(256), 0, stream, x, xT);
    hipLaunchKernelGGL(pack_w,      dim3(2304), dim3(256), 0, stream, wt, w3);
    hipLaunchKernelGGL(dcn_main,    dim3(576),  dim3(256), 0, stream,
                       off, msk, xT, w3, convOut, stats);
    hipLaunchKernelGGL(gn_final,    dim3(576),  dim3(256), 0, stream,
                       convOut, stats, gamma, beta, out);
}

// Round 6
// 183.061 us; speedup vs baseline: 1.7619x; 1.1812x over previous
//
#include <hip/hip_runtime.h>
#include <hip/hip_bf16.h>
#include <stdint.h>

typedef __attribute__((ext_vector_type(4))) float f32x4;
typedef __attribute__((ext_vector_type(8))) short s16x8;
typedef __attribute__((ext_vector_type(4))) unsigned int u32x4;
typedef unsigned short u16;
typedef unsigned int u32;

#define B_ 4
#define C_ 256
#define O_ 256
#define H_ 96
#define W_ 96
#define HW_ (H_*W_)      /* 9216 */
#define M_ (B_*HW_)      /* 36864 */

static __device__ __forceinline__ float asf(u32 u){
    union { u32 u; float f; } x; x.u = u; return x.f;
}
static __device__ __forceinline__ u16 f2bf(float f){
    union { float f; u32 u; } x; x.f = f;
    u32 u = x.u;
    u32 r = (u + 0x7fffu + ((u >> 16) & 1u)) >> 16;
    return (u16)r;
}
// bilinear-combine a bf16 pair (packed in u32) from 4 source pairs, repack
static __device__ __forceinline__ u32 blerp_pack(u32 q00, u32 q01, u32 q10, u32 q11,
                                                 float w00, float w01, float w10, float w11)
{
    float f0 = asf(q00 << 16) * w00 + asf(q01 << 16) * w01
             + asf(q10 << 16) * w10 + asf(q11 << 16) * w11;
    float f1 = asf(q00) * w00 + asf(q01) * w01 + asf(q10) * w10 + asf(q11) * w11;
    float2 fp; fp.x = f0; fp.y = f1;
    __hip_bfloat162 hb = __float22bfloat162_rn(fp);
    union { __hip_bfloat162 h; u32 u; } cv; cv.h = hb;
    return cv.u;
}

struct TapCtx {
    float w00, w01, w10, w11;
    const u16 *r00, *r01, *r10, *r11;
};

static __device__ __forceinline__ TapCtx tap_setup(
    int tap, int b, int h, int w, int hw,
    const float* __restrict__ off, const float* __restrict__ msk,
    const u16* __restrict__ xT)
{
    TapCtx t;
    float dy = off[(size_t)(b * 18 + 2 * tap) * HW_ + hw];
    float dx = off[(size_t)(b * 18 + 2 * tap + 1) * HW_ + hw];
    float mk = msk[(size_t)(b * 9 + tap) * HW_ + hw];
    float py = (float)(h + tap / 3 - 1) + dy;
    float px = (float)(w + tap % 3 - 1) + dx;
    float fy = floorf(py), fx = floorf(px);
    float wy = py - fy, wx = px - fx;
    int y0 = (int)fy, x0 = (int)fx;
    int y1 = y0 + 1, x1 = x0 + 1;
    float w00 = (1.f - wy) * (1.f - wx) * mk;
    float w01 = (1.f - wy) * wx * mk;
    float w10 = wy * (1.f - wx) * mk;
    float w11 = wy * wx * mk;
    if (y0 < 0 || y0 >= H_) { w00 = 0.f; w01 = 0.f; }
    if (y1 < 0 || y1 >= H_) { w10 = 0.f; w11 = 0.f; }
    if (x0 < 0 || x0 >= W_) { w00 = 0.f; w10 = 0.f; }
    if (x1 < 0 || x1 >= W_) { w01 = 0.f; w11 = 0.f; }
    int cy0 = min(max(y0, 0), H_ - 1), cy1 = min(max(y1, 0), H_ - 1);
    int cx0 = min(max(x0, 0), W_ - 1), cx1 = min(max(x1, 0), W_ - 1);
    size_t rb = (size_t)b * HW_ * C_;
    t.r00 = xT + rb + ((size_t)cy0 * W_ + cx0) * C_;
    t.r01 = xT + rb + ((size_t)cy0 * W_ + cx1) * C_;
    t.r10 = xT + rb + ((size_t)cy1 * W_ + cx0) * C_;
    t.r11 = xT + rb + ((size_t)cy1 * W_ + cx1) * C_;
    t.w00 = w00; t.w01 = w01; t.w10 = w10; t.w11 = w11;
    return t;
}

// ---------------------------------------------------------------------------
// Kernel 1: transpose x [B,C,H,W] f32 -> xT [B,H,W,C] bf16
// ---------------------------------------------------------------------------
__global__ __launch_bounds__(256) void transpose_x(const float* __restrict__ x,
                                                   u16* __restrict__ xT)
{
    __shared__ float t[32][33];
    int tid = threadIdx.x;
    int tx = tid & 31, ty = tid >> 5;          // 32 x 8
    int bi = blockIdx.x;
    int w0 = (bi % 3) * 32;
    int c0 = ((bi / 3) % 8) * 32;
    int bh = bi / 24;                           // b*H + h  (0..383)
    int b = bh / H_, h = bh - b * H_;
    #pragma unroll
    for (int r = 0; r < 4; ++r){
        int c = c0 + ty + r * 8;
        t[ty + r * 8][tx] = x[(size_t)(b * C_ + c) * HW_ + h * W_ + w0 + tx];
    }
    __syncthreads();
    #pragma unroll
    for (int r = 0; r < 4; ++r){
        int w = w0 + ty + r * 8;
        xT[((size_t)(b * H_ + h) * W_ + w) * C_ + c0 + tx] = f2bf(t[tx][ty + r * 8]);
    }
}

// ---------------------------------------------------------------------------
// Kernel 2: pack weight [O,C,3,3] f32 -> W3 bf16:
//   kidx = tap*256 + c ; flat u16 index = (kidx>>3)*2048 + o*8 + (kidx&7)
// ---------------------------------------------------------------------------
__global__ __launch_bounds__(256) void pack_w(const float* __restrict__ wt,
                                              u16* __restrict__ w3)
{
    int n = blockIdx.x * 256 + threadIdx.x;     // < 589824 = 256*256*9
    int o = n / 2304;
    int rem = n - o * 2304;
    int c = rem / 9;
    int tap = rem - c * 9;
    int kidx = tap * 256 + c;
    w3[(size_t)(kidx >> 3) * 2048 + o * 8 + (kidx & 7)] = f2bf(wt[n]);
}

// ---------------------------------------------------------------------------
// Kernel 3: main deformable-conv implicit GEMM.
// 576 blocks x 512 threads (8 waves). Block = 8x8 px patch, BM=64, BN=256.
// Each wave owns 64px x 32cols (acc[4][2] = 32 VGPR) -> w3 traffic stays at
// 663 MB total. Direct scattered gather from L2 (XCD-contiguous tile swizzle
// keeps each XCD's working set in its private L2); 16 waves/CU for MLP.
// ---------------------------------------------------------------------------
__global__ __launch_bounds__(512, 4) void dcn_main(
    const float* __restrict__ off, const float* __restrict__ msk,
    const u16* __restrict__ xT, const u16* __restrict__ w3,
    float* __restrict__ convOut, float* __restrict__ stats)
{
    __shared__ u16 At[64 * 256];     // 32 KB, rows of 512B, 16B-chunk XOR swz
    int tid = threadIdx.x;
    int lane = tid & 63;
    int wv = tid >> 6;               // 0..7 : 32-col chunk (= GN group!)
    int l15 = lane & 15;
    int g = lane >> 4;               // 0..3

    int bid = blockIdx.x;
    int tile = (bid & 7) * 72 + (bid >> 3);     // 576 = 8*72, bijective
    int b = tile / 144;
    int t = tile - b * 144;
    int ty_ = t / 12, tx_ = t - ty_ * 12;
    int py0 = ty_ * 8, px0 = tx_ * 8;

    f32x4 acc[4][2];
    #pragma unroll
    for (int i = 0; i < 4; ++i)
        #pragma unroll
        for (int q = 0; q < 2; ++q)
            acc[i][q] = (f32x4){0.f, 0.f, 0.f, 0.f};

    // gather assignment: 8 threads per pixel, 32 channels each
    int p = tid >> 3;                // pixel 0..63 within patch
    int k = tid & 7;
    int h = py0 + (p >> 3);
    int w = px0 + (p & 7);
    int hw = h * W_ + w;

    for (int tap = 0; tap < 9; ++tap){
        __syncthreads();  // previous tap's LDS reads complete
        TapCtx tp = tap_setup(tap, b, h, w, hw, off, msk, xT);
        // ---- gather: 4 iters, each a 16B chunk per thread ----
        #pragma unroll
        for (int i = 0; i < 4; ++i){
            int ck = k + i * 8;                 // chunk 0..31 (8 ch each)
            int c = ck * 8;
            u32x4 q00 = *(const u32x4*)(tp.r00 + c);
            u32x4 q01 = *(const u32x4*)(tp.r01 + c);
            u32x4 q10 = *(const u32x4*)(tp.r10 + c);
            u32x4 q11 = *(const u32x4*)(tp.r11 + c);
            u32x4 outv;
            #pragma unroll
            for (int j = 0; j < 4; ++j)
                outv[j] = blerp_pack(q00[j], q01[j], q10[j], q11[j],
                                     tp.w00, tp.w01, tp.w10, tp.w11);
            u32 boff = (u32)(p * 512) + (u32)((ck ^ (p & 15)) << 4);
            *(u32x4*)((char*)At + boff) = outv;
        }
        __syncthreads();
        // ---- MFMA: 8 K-steps over this tap's 256 channels ----
        __builtin_amdgcn_s_setprio(1);
        #pragma unroll
        for (int step = 0; step < 8; ++step){
            int ck = step * 4 + g;              // a-chunk 0..31
            s16x8 a[4];
            #pragma unroll
            for (int i = 0; i < 4; ++i){
                int r = i * 16 + l15;
                u32 boff = (u32)(r * 512) + (u32)((ck ^ (r & 15)) << 4);
                a[i] = *(const s16x8*)((const char*)At + boff);
            }
            const u16* wrow = w3 + (size_t)(tap * 32 + step * 4 + g) * 2048
                            + (size_t)(wv * 32 + l15) * 8;
            s16x8 b0 = *(const s16x8*)(wrow);
            s16x8 b1 = *(const s16x8*)(wrow + 128);
            #pragma unroll
            for (int i = 0; i < 4; ++i){
                acc[i][0] = __builtin_amdgcn_mfma_f32_16x16x32_bf16(a[i], b0, acc[i][0], 0, 0, 0);
                acc[i][1] = __builtin_amdgcn_mfma_f32_16x16x32_bf16(a[i], b1, acc[i][1], 0, 0, 0);
            }
        }
        __builtin_amdgcn_s_setprio(0);
    }

    // ---- epilogue: store conv f32 at global [m][o], accumulate GN stats ----
    float s0 = 0.f, s20 = 0.f;
    size_t mbase = (size_t)b * HW_;
    #pragma unroll
    for (int i = 0; i < 4; ++i){
        #pragma unroll
        for (int q = 0; q < 2; ++q){
            int oc = wv * 32 + q * 16 + l15;
            #pragma unroll
            for (int j = 0; j < 4; ++j){
                float v = acc[i][q][j];
                int pp = i * 16 + g * 4 + j;              // pixel in patch
                int mr_hw = (py0 + (pp >> 3)) * W_ + px0 + (pp & 7);
                convOut[(mbase + mr_hw) * 256 + oc] = v;
                s0 += v; s20 += v * v;
            }
        }
    }
    #pragma unroll
    for (int d = 32; d; d >>= 1){
        s0  += __shfl_xor(s0, d, 64);
        s20 += __shfl_xor(s20, d, 64);
    }
    if (lane == 0){
        atomicAdd(&stats[(b * 8 + wv) * 2 + 0], s0);
        atomicAdd(&stats[(b * 8 + wv) * 2 + 1], s20);
    }
}

// ---------------------------------------------------------------------------
// Kernel 4: GroupNorm(8) + ReLU, transposing [m][o] -> [b,o,h,w]
// ---------------------------------------------------------------------------
__global__ __launch_bounds__(256) void gn_final(
    const float* __restrict__ convOut, const float* __restrict__ stats,
    const float* __restrict__ gamma, const float* __restrict__ beta,
    float* __restrict__ out)
{
    __shared__ float t[64][257];
    int tid = threadIdx.x;
    int m0 = blockIdx.x * 64;
    int b = m0 / HW_;
    const f32x4* src = (const f32x4*)(convOut + (size_t)m0 * 256);
    #pragma unroll
    for (int it = 0; it < 16; ++it){
        int idx = it * 256 + tid;
        int r = idx >> 6;
        int c4 = idx & 63;
        f32x4 v = src[(size_t)r * 64 + c4];
        t[r][c4 * 4 + 0] = v[0];
        t[r][c4 * 4 + 1] = v[1];
        t[r][c4 * 4 + 2] = v[2];
        t[r][c4 * 4 + 3] = v[3];
    }
    __syncthreads();
    int lanem = tid & 63;
    int hw = (m0 - b * HW_) + lanem;
    float* dst = out + (size_t)b * O_ * HW_ + hw;
    const float invN = 1.f / 294912.f;   // 32 ch * 9216 px
    #pragma unroll 8
    for (int it = 0; it < 64; ++it){
        int o = it * 4 + (tid >> 6);
        int gidx = (b * 8 + (o >> 5)) * 2;
        float sm = stats[gidx + 0];
        float sq = stats[gidx + 1];
        float mu = sm * invN;
        float var = sq * invN - mu * mu;
        float inv = rsqrtf(var + 1e-5f);
        float sc = gamma[o] * inv;
        float sh = beta[o] - mu * sc;
        float v = t[lanem][o];
        dst[(size_t)o * HW_] = fmaxf(v * sc + sh, 0.f);
    }
}

// ---------------------------------------------------------------------------
extern "C" void kernel_launch(void* const* d_in, const int* in_sizes, int n_in,
                              void* d_out, int out_size, void* d_ws, size_t ws_size,
                              hipStream_t stream)
{
    const float* x     = (const float*)d_in[0];
    const float* off   = (const float*)d_in[1];
    const float* msk   = (const float*)d_in[2];
    const float* wt    = (const float*)d_in[3];
    const float* gamma = (const float*)d_in[4];
    const float* beta  = (const float*)d_in[5];
    float* out = (float*)d_out;

    char* ws = (char*)d_ws;
    u16*   xT      = (u16*)ws;                       // 18,874,368 B
    u16*   w3      = (u16*)(ws + 18874368);          //  1,179,648 B
    float* convOut = (float*)(ws + 20054016);        // 37,748,736 B
    float* stats   = (float*)(ws + 57802752);        //        256 B

    hipMemsetAsync(stats, 0, 256, stream);
    hipLaunchKernelGGL(transpose_x, dim3(9216), dim3(256), 0, stream, x, xT);
    hipLaunchKernelGGL(pack_w,      dim3(2304), dim3(256), 0, stream, wt, w3);
    hipLaunchKernelGGL(dcn_main,    dim3(576),  dim3(512), 0, stream,
                       off, msk, xT, w3, convOut, stats);
    hipLaunchKernelGGL(gn_final,    dim3(576),  dim3(256), 0, stream,
                       convOut, stats, gamma, beta, out);
}